// Round 6
// baseline (89.623 us; speedup 1.0000x reference)
//
#include <hip/hip_runtime.h>
#include <hip/hip_bf16.h>
#include <math.h>

#define BB 2
#define NN 2048
#define FF 128
#define HH 4
#define HALF 1024

typedef __attribute__((ext_vector_type(8))) short short8;
typedef __attribute__((ext_vector_type(4))) float f32x4;

__device__ __forceinline__ short f2bf(float f){
    __hip_bfloat16 h = __float2bfloat16(f);
    return *reinterpret_cast<short*>(&h);
}
__device__ __forceinline__ float bf2f(short v){
    __hip_bfloat16 h = *reinterpret_cast<__hip_bfloat16*>(&v);
    return __bfloat162float(h);
}

// K0: wv fp32 -> wvB (bf16 row-major) + wvT (bf16 transpose)
__global__ void k_transpose(const float* __restrict__ wv, __hip_bfloat16* __restrict__ wvT,
                            __hip_bfloat16* __restrict__ wvB){
    __shared__ float tile[32][33];
    int b = blockIdx.z;
    int i0 = blockIdx.x * 32, j0 = blockIdx.y * 32;
    int tx = threadIdx.x & 31, ty = threadIdx.x >> 5;
    const float* src = wv + (size_t)b * HALF * HALF;
    __hip_bfloat16* dstT = wvT + (size_t)b * HALF * HALF;
    __hip_bfloat16* dstB = wvB + (size_t)b * HALF * HALF;
    #pragma unroll
    for(int l = 0; l < 4; l++){
        int row = ty + l * 8;
        float v = src[(size_t)(j0 + row) * HALF + (i0 + tx)];
        tile[row][tx] = v;
        dstB[(size_t)(j0 + row) * HALF + (i0 + tx)] = __float2bfloat16(v);
    }
    __syncthreads();
    #pragma unroll
    for(int l = 0; l < 4; l++){
        int row = ty + l * 8;
        dstT[(size_t)(i0 + row) * HALF + (j0 + tx)] = __float2bfloat16(tile[tx][row]);
    }
}

// K1: Wh[b][h][n][f] = sum_k x[b][n][k] * W[h][k][f]   (fp32)
__global__ void k_wh(const float* __restrict__ x, const float* __restrict__ W,
                     float* __restrict__ Wh){
    __shared__ float xs[32][FF];
    int n0 = blockIdx.x * 32;
    int h  = blockIdx.y;
    int b  = blockIdx.z;
    int t  = threadIdx.x;
    const float* xb = x + ((size_t)b * NN + n0) * FF;
    #pragma unroll
    for(int l = 0; l < 16; l++){
        int idx = l * 256 + t;
        xs[idx >> 7][idx & 127] = xb[idx];
    }
    __syncthreads();
    int f = t & 127, rh = t >> 7;
    float acc[16];
    #pragma unroll
    for(int r = 0; r < 16; r++) acc[r] = 0.f;
    const float* Wp = W + (size_t)h * FF * FF + f;
    for(int k = 0; k < FF; k++){
        float w = Wp[(size_t)k * FF];
        #pragma unroll
        for(int r = 0; r < 16; r++) acc[r] += xs[rh * 16 + r][k] * w;
    }
    float* o = Wh + (((size_t)b * HH + h) * NN + n0 + rh * 16) * FF + f;
    #pragma unroll
    for(int r = 0; r < 16; r++) o[(size_t)r * FF] = acc[r];
}

// K2: s/d row dots + zero denom (replaces hipMemsetAsync)
__global__ void k_sd(const float* __restrict__ Wh, const float* __restrict__ a,
                     float* __restrict__ s, float* __restrict__ d, float* __restrict__ denom){
    int gid = blockIdx.x * blockDim.x + threadIdx.x;
    if(gid < BB * HH * NN) denom[gid] = 0.f;
    int wid = threadIdx.x >> 6, lane = threadIdx.x & 63;
    int row = blockIdx.x * 4 + wid;
    int h = (row / NN) & (HH - 1);
    const float* wr = Wh + (size_t)row * FF;
    float v0 = wr[lane], v1 = wr[lane + 64];
    const float* ah = a + (size_t)h * 2 * FF;
    float ps = v0 * ah[lane]      + v1 * ah[lane + 64];
    float pd = v0 * ah[FF + lane] + v1 * ah[FF + lane + 64];
    #pragma unroll
    for(int m = 32; m >= 1; m >>= 1){
        ps += __shfl_xor(ps, m);
        pd += __shfl_xor(pd, m);
    }
    if(lane == 0){ s[row] = ps; d[row] = pd; }
}

// K3: P (bf16, MFMA-A-fragment layout) + column-sum denom via atomics.
// ONE HEAD PER BLOCK: per-thread state = dv_[8]+accd[8] (~40 VGPR, no spill).
// P offset = ((slice*64 + mtg)*32 + ktg)*512 + lane*8, slice = bb*4+h.
// grid: x = jt(8: 128 j), y = it(32: 32 i), z = bb*h(16). block 256.
__global__ __launch_bounds__(256) void k_att(const int* __restrict__ adj,
        const __hip_bfloat16* __restrict__ wvRM, const __hip_bfloat16* __restrict__ wvTp,
        const float* __restrict__ s, const float* __restrict__ d,
        short* __restrict__ P, float* __restrict__ denom){
    int t = threadIdx.x;
    int w = t >> 6, lane = t & 63, q = lane >> 4, r = lane & 15;
    int jt = blockIdx.x, it = blockIdx.y, z = blockIdx.z;
    int bb = z >> 2, h = z & 3;
    int b = bb >> 1, blk = bb & 1;
    int jl = jt * 128 + w * 32 + q * 8;
    int jg = blk ? jl : HALF + jl;
    int sl = b * HH + h;
    const float* dp = d + (size_t)sl * NN + jg;
    float4 d0 = *(const float4*)dp;
    float4 d1 = *(const float4*)(dp + 4);
    float dv_[8] = {d0.x, d0.y, d0.z, d0.w, d1.x, d1.y, d1.z, d1.w};
    float accd[8] = {};
    int ktg = jt * 4 + w;
    #pragma unroll
    for(int mtl = 0; mtl < 2; mtl++){
        int iloc = it * 32 + mtl * 16 + r;
        int ig = blk ? HALF + iloc : iloc;
        const int* ap = adj + ((size_t)b * NN + ig) * NN + jg;
        int4 A0 = *(const int4*)ap;
        int4 A1 = *(const int4*)(ap + 4);
        int aa[8] = {A0.x, A0.y, A0.z, A0.w, A1.x, A1.y, A1.z, A1.w};
        const short* wp = (const short*)(blk ? wvRM : wvTp) + ((size_t)b * HALF + iloc) * HALF + jl;
        short8 wb = *(const short8*)wp;
        float sv = s[(size_t)sl * NN + ig];
        int mtg = it * 2 + mtl;
        short8 pk;
        #pragma unroll
        for(int e = 0; e < 8; e++){
            float wm = aa[e] > 0 ? bf2f(wb[e]) : 0.f;
            float tt = sv + dv_[e];
            tt = tt > 0.f ? tt : 0.2f * tt;
            float pe = __expf(tt) * wm;
            accd[e] += pe;
            pk[e] = f2bf(pe);
        }
        *(short8*)(P + (((size_t)(bb * HH + h) * 64 + mtg) * 32 + ktg) * 512 + lane * 8) = pk;
    }
    #pragma unroll
    for(int e = 0; e < 8; e++){
        float v = accd[e];
        v += __shfl_xor(v, 1);
        v += __shfl_xor(v, 2);
        v += __shfl_xor(v, 4);
        v += __shfl_xor(v, 8);
        accd[e] = v;
    }
    if(r == 0){
        #pragma unroll
        for(int e = 0; e < 8; e++)
            atomicAdd(&denom[(size_t)sl * NN + jg + e], accd[e]);
    }
}

// K4: WhB (bf16, MFMA-B-fragment layout) = Wh[j][f] * 1/clip(denom[j])
__global__ __launch_bounds__(256) void k_scale(const float* __restrict__ Wh,
        const float* __restrict__ denom, short* __restrict__ WhB){
    int t = threadIdx.x, w = t >> 6, lane = t & 63, q = lane >> 4, r = lane & 15;
    int kt = blockIdx.x, h = blockIdx.y, b = blockIdx.z;
    int sl = b * HH + h;
    int jb = kt * 32 + q * 8;
    const float* dp = denom + (size_t)sl * NN + jb;
    float4 D0 = *(const float4*)dp;
    float4 D1 = *(const float4*)(dp + 4);
    float dn[8] = {D0.x,D0.y,D0.z,D0.w,D1.x,D1.y,D1.z,D1.w};
    float inv[8];
    #pragma unroll
    for(int e = 0; e < 8; e++) inv[e] = 1.f / fmaxf(dn[e], 1e-12f);
    #pragma unroll
    for(int ntl = 0; ntl < 2; ntl++){
        int nt = w + ntl * 4;
        int f = nt * 16 + r;
        short8 pk;
        #pragma unroll
        for(int e = 0; e < 8; e++){
            float v = Wh[((size_t)sl * NN + jb + e) * FF + f] * inv[e];
            pk[e] = f2bf(v);
        }
        *(short8*)(WhB + (((size_t)sl * 8 + nt) * 64 + kt) * 512 + lane * 8) = pk;
    }
}

// K5: out = ELU(P @ WhB). BM=32, grid (32,4,4)=512 blocks, 4 waves (2m x 2n).
// LDS frags per buf: [0,1]=A(mtg 0,1), [2..9]=B(nt 0..7). 1KB per frag.
__global__ __launch_bounds__(256) void k_pv(const short* __restrict__ P,
        const short* __restrict__ WhB, float* __restrict__ out){
    __shared__ short lds[2][5120];
    int t = threadIdx.x;
    int w = t >> 6, lane = t & 63;
    int wm = w >> 1, wn = w & 1;
    int mt = blockIdx.x, h = blockIdx.y, bb = blockIdx.z;
    int b = bb >> 1, blk = bb & 1;
    size_t Pbase = ((size_t)bb * HH + h) * 64 + mt * 2;
    size_t Bb2 = ((size_t)b * HH + h) * 8;
    int koff = blk ? 0 : 32;   // blk=0 rows attend to global cols 1024..2047
    f32x4 acc[4] = {};
    short8 r0, r1, r2;
#define SADDR(IDX, KT) ((IDX) < 128 ? \
    (P + ((Pbase + ((IDX) >> 6)) * 32 + (KT)) * 512 + ((IDX) & 63) * 8) : \
    (WhB + ((Bb2 + (((IDX) - 128) >> 6)) * 64 + koff + (KT)) * 512 + (((IDX) - 128) & 63) * 8))
#define LOADST(KT) { \
    r0 = *(const short8*)SADDR(t, KT); \
    r1 = *(const short8*)SADDR(t + 256, KT); \
    if(t < 128) r2 = *(const short8*)SADDR(t + 512, KT); }
#define WRITEST(BUF) { \
    *(short8*)&lds[BUF][t * 8] = r0; \
    *(short8*)&lds[BUF][(t + 256) * 8] = r1; \
    if(t < 128) *(short8*)&lds[BUF][(t + 512) * 8] = r2; }
    LOADST(0)
    WRITEST(0)
    __syncthreads();
    for(int kt = 0; kt < 32; kt++){
        int cur = kt & 1;
        if(kt < 31){ LOADST(kt + 1) }
        short8 af = *(const short8*)&lds[cur][(wm * 64 + lane) * 8];
        short8 bf[4];
        #pragma unroll
        for(int ni = 0; ni < 4; ni++)
            bf[ni] = *(const short8*)&lds[cur][((2 + wn * 4 + ni) * 64 + lane) * 8];
        #pragma unroll
        for(int ni = 0; ni < 4; ni++)
            acc[ni] = __builtin_amdgcn_mfma_f32_16x16x32_bf16(af, bf[ni], acc[ni], 0, 0, 0);
        __syncthreads();
        if(kt < 31){
            WRITEST(cur ^ 1)
            __syncthreads();
        }
    }
    int rq = lane >> 4, rc = lane & 15;
    int rowg0 = (blk ? HALF : 0) + mt * 32 + wm * 16;
    #pragma unroll
    for(int ni = 0; ni < 4; ni++){
        int f = (wn * 4 + ni) * 16 + rc;
        #pragma unroll
        for(int rg = 0; rg < 4; rg++){
            float v = acc[ni][rg];
            v = v > 0.f ? v : expm1f(v);
            out[((size_t)b * NN + rowg0 + rq * 4 + rg) * (HH * FF) + h * FF + f] = v;
        }
    }
#undef SADDR
#undef LOADST
#undef WRITEST
}

extern "C" void kernel_launch(void* const* d_in, const int* in_sizes, int n_in,
                              void* d_out, int out_size, void* d_ws, size_t ws_size,
                              hipStream_t stream){
    const float* x   = (const float*)d_in[0];
    const float* wv  = (const float*)d_in[1];
    const float* W   = (const float*)d_in[2];
    const float* a   = (const float*)d_in[3];
    const int*   adj = (const int*)d_in[4];
    float* out = (float*)d_out;

    char* ws = (char*)d_ws;
    short*          P     = (short*)ws;                          // 33,554,432 B
    float*          Wh    = (float*)(ws + 33554432);             //  8,388,608 B
    short*          WhB   = (short*)(ws + 41943040);             //  4,194,304 B
    __hip_bfloat16* wvT   = (__hip_bfloat16*)(ws + 46137344);    //  4,194,304 B
    __hip_bfloat16* wvB   = (__hip_bfloat16*)(ws + 50331648);    //  4,194,304 B
    float*          s     = (float*)(ws + 54525952);             //     65,536 B
    float*          dv    = (float*)(ws + 54591488);             //     65,536 B
    float*          denom = (float*)(ws + 54657024);             //     65,536 B

    k_transpose<<<dim3(32, 32, BB), 256, 0, stream>>>(wv, wvT, wvB);
    k_wh<<<dim3(64, HH, BB), 256, 0, stream>>>(x, W, Wh);
    k_sd<<<dim3(4096), 256, 0, stream>>>(Wh, a, s, dv, denom);
    k_att<<<dim3(8, 32, 16), 256, 0, stream>>>(adj, wvB, wvT, s, dv, P, denom);
    k_scale<<<dim3(64, HH, BB), 256, 0, stream>>>(Wh, denom, WhB);
    k_pv<<<dim3(32, HH, 4), 256, 0, stream>>>(P, WhB, out);
}

// Round 7
// 70.310 us; speedup vs baseline: 1.2747x; 1.2747x over previous
//
#include <hip/hip_runtime.h>
#include <hip/hip_bf16.h>
#include <math.h>

#define BB 2
#define NN 2048
#define FF 128
#define HH 4
#define HALF 1024

typedef __attribute__((ext_vector_type(8))) short short8;
typedef __attribute__((ext_vector_type(4))) float f32x4;

__device__ __forceinline__ short f2bf(float f){
    __hip_bfloat16 h = __float2bfloat16(f);
    return *reinterpret_cast<short*>(&h);
}
__device__ __forceinline__ float bf2f(short v){
    __hip_bfloat16 h = *reinterpret_cast<__hip_bfloat16*>(&v);
    return __bfloat162float(h);
}

// K0: wv fp32 -> wvB (bf16 row-major) + wvT (bf16 transpose)
__global__ void k_transpose(const float* __restrict__ wv, __hip_bfloat16* __restrict__ wvT,
                            __hip_bfloat16* __restrict__ wvB){
    __shared__ float tile[32][33];
    int b = blockIdx.z;
    int i0 = blockIdx.x * 32, j0 = blockIdx.y * 32;
    int tx = threadIdx.x & 31, ty = threadIdx.x >> 5;
    const float* src = wv + (size_t)b * HALF * HALF;
    __hip_bfloat16* dstT = wvT + (size_t)b * HALF * HALF;
    __hip_bfloat16* dstB = wvB + (size_t)b * HALF * HALF;
    #pragma unroll
    for(int l = 0; l < 4; l++){
        int row = ty + l * 8;
        float v = src[(size_t)(j0 + row) * HALF + (i0 + tx)];
        tile[row][tx] = v;
        dstB[(size_t)(j0 + row) * HALF + (i0 + tx)] = __float2bfloat16(v);
    }
    __syncthreads();
    #pragma unroll
    for(int l = 0; l < 4; l++){
        int row = ty + l * 8;
        dstT[(size_t)(i0 + row) * HALF + (j0 + tx)] = __float2bfloat16(tile[tx][row]);
    }
}

// K1: Wh[b][h][n][f] = sum_k x[b][n][k] * W[h][k][f]   (fp32)
__global__ void k_wh(const float* __restrict__ x, const float* __restrict__ W,
                     float* __restrict__ Wh){
    __shared__ float xs[32][FF];
    int n0 = blockIdx.x * 32;
    int h  = blockIdx.y;
    int b  = blockIdx.z;
    int t  = threadIdx.x;
    const float* xb = x + ((size_t)b * NN + n0) * FF;
    #pragma unroll
    for(int l = 0; l < 16; l++){
        int idx = l * 256 + t;
        xs[idx >> 7][idx & 127] = xb[idx];
    }
    __syncthreads();
    int f = t & 127, rh = t >> 7;
    float acc[16];
    #pragma unroll
    for(int r = 0; r < 16; r++) acc[r] = 0.f;
    const float* Wp = W + (size_t)h * FF * FF + f;
    for(int k = 0; k < FF; k++){
        float w = Wp[(size_t)k * FF];
        #pragma unroll
        for(int r = 0; r < 16; r++) acc[r] += xs[rh * 16 + r][k] * w;
    }
    float* o = Wh + (((size_t)b * HH + h) * NN + n0 + rh * 16) * FF + f;
    #pragma unroll
    for(int r = 0; r < 16; r++) o[(size_t)r * FF] = acc[r];
}

// K2: row dots -> TRANSPOSED sT/dT [b][n][h] (+ zero denom)
__global__ void k_sd(const float* __restrict__ Wh, const float* __restrict__ a,
                     float* __restrict__ sT, float* __restrict__ dT, float* __restrict__ denom){
    int gid = blockIdx.x * blockDim.x + threadIdx.x;
    if(gid < BB * HH * NN) denom[gid] = 0.f;
    int wid = threadIdx.x >> 6, lane = threadIdx.x & 63;
    int row = blockIdx.x * 4 + wid;            // row = (b*HH + h)*NN + n
    int b = row >> 13, h = (row >> 11) & 3, n = row & (NN - 1);
    const float* wr = Wh + (size_t)row * FF;
    float v0 = wr[lane], v1 = wr[lane + 64];
    const float* ah = a + (size_t)h * 2 * FF;
    float ps = v0 * ah[lane]      + v1 * ah[lane + 64];
    float pd = v0 * ah[FF + lane] + v1 * ah[FF + lane + 64];
    #pragma unroll
    for(int m = 32; m >= 1; m >>= 1){
        ps += __shfl_xor(ps, m);
        pd += __shfl_xor(pd, m);
    }
    if(lane == 0){
        sT[((size_t)b * NN + n) * HH + h] = ps;
        dT[((size_t)b * NN + n) * HH + h] = pd;
    }
}

// K3: ROW-MAJOR streaming attention: P[slice][i_loc][j_loc] bf16 + column denoms.
// Thread owns column jl, walks 16 consecutive rows; all loads coalesced, heads in-register.
// grid: x = jt(8: 128 j), y = ic(32: 32 i), z = bb(4). block 256 (jlane 128 x ihalf 2).
__global__ __launch_bounds__(256) void k_att(const int* __restrict__ adj,
        const __hip_bfloat16* __restrict__ wvRM, const __hip_bfloat16* __restrict__ wvTp,
        const float* __restrict__ sT, const float* __restrict__ dT,
        short* __restrict__ P, float* __restrict__ denom){
    __shared__ float red[HH][128];
    int t = threadIdx.x;
    int jlane = t & 127, ihalf = t >> 7;
    int jt = blockIdx.x, ic = blockIdx.y, bb = blockIdx.z;
    int b = bb >> 1, blk = bb & 1;
    int jl = jt * 128 + jlane;                 // quadrant-local col
    int jg = blk ? jl : HALF + jl;             // global col
    int iloc0 = ic * 32 + ihalf * 16;          // quadrant-local row base
    int ig0 = (blk ? HALF : 0) + iloc0;        // global row base
    const int* ap = adj + ((size_t)b * NN + ig0) * NN + jg;
    const short* wp = (const short*)(blk ? wvRM : wvTp) + ((size_t)b * HALF + iloc0) * HALF + jl;
    const float* sp = sT + ((size_t)b * NN + ig0) * HH;
    float4 dv4 = *(const float4*)(dT + ((size_t)b * NN + jg) * HH);
    float da[4] = {dv4.x, dv4.y, dv4.z, dv4.w};
    short* Pp = P + ((size_t)(bb * HH) << 20) + (size_t)iloc0 * 1024 + jl;
    float den[HH] = {};
    #pragma unroll 4
    for(int ii = 0; ii < 16; ii++){
        int av = ap[(size_t)ii * NN];
        short wq = wp[(size_t)ii * HALF];
        float4 s4 = *(const float4*)(sp + ii * HH);
        float wm = av > 0 ? bf2f(wq) : 0.f;
        float sa[4] = {s4.x, s4.y, s4.z, s4.w};
        #pragma unroll
        for(int h = 0; h < HH; h++){
            float tt = sa[h] + da[h];
            tt = tt > 0.f ? tt : 0.2f * tt;
            float pe = __expf(tt) * wm;
            den[h] += pe;
            Pp[((size_t)h << 20) + (size_t)ii * 1024] = f2bf(pe);
        }
    }
    if(ihalf){
        #pragma unroll
        for(int h = 0; h < HH; h++) red[h][jlane] = den[h];
    }
    __syncthreads();
    if(!ihalf){
        #pragma unroll
        for(int h = 0; h < HH; h++)
            atomicAdd(&denom[((size_t)b * HH + h) * NN + jg], den[h] + red[h][jlane]);
    }
}

// K4: WhB (bf16, MFMA-B-fragment layout) = Wh[j][f] * 1/clip(denom[j])
__global__ __launch_bounds__(256) void k_scale(const float* __restrict__ Wh,
        const float* __restrict__ denom, short* __restrict__ WhB){
    int t = threadIdx.x, w = t >> 6, lane = t & 63, q = lane >> 4, r = lane & 15;
    int kt = blockIdx.x, h = blockIdx.y, b = blockIdx.z;
    int sl = b * HH + h;
    int jb = kt * 32 + q * 8;
    const float* dp = denom + (size_t)sl * NN + jb;
    float4 D0 = *(const float4*)dp;
    float4 D1 = *(const float4*)(dp + 4);
    float dn[8] = {D0.x,D0.y,D0.z,D0.w,D1.x,D1.y,D1.z,D1.w};
    float inv[8];
    #pragma unroll
    for(int e = 0; e < 8; e++) inv[e] = 1.f / fmaxf(dn[e], 1e-12f);
    #pragma unroll
    for(int ntl = 0; ntl < 2; ntl++){
        int nt = w + ntl * 4;
        int f = nt * 16 + r;
        short8 pk;
        #pragma unroll
        for(int e = 0; e < 8; e++){
            float v = Wh[((size_t)sl * NN + jb + e) * FF + f] * inv[e];
            pk[e] = f2bf(v);
        }
        *(short8*)(WhB + (((size_t)sl * 8 + nt) * 64 + kt) * 512 + lane * 8) = pk;
    }
}

// K5: out = ELU(P @ WhB). A-frags assembled from ROW-MAJOR P during staging.
// BM=32, grid (32,4,4)=512 blocks, 4 waves (2m x 2n). LDS: [0,1]=A, [2..9]=B, 1KB/frag.
__global__ __launch_bounds__(256) void k_pv(const short* __restrict__ P,
        const short* __restrict__ WhB, float* __restrict__ out){
    __shared__ short lds[2][5120];
    int t = threadIdx.x;
    int w = t >> 6, lane = t & 63;
    int wm = w >> 1, wn = w & 1;
    int mt = blockIdx.x, h = blockIdx.y, bb = blockIdx.z;
    int b = bb >> 1, blk = bb & 1;
    const short* Prow = P + ((size_t)(bb * HH + h) << 20);   // [1024][1024] local
    size_t Bb2 = ((size_t)b * HH + h) * 8;
    int koff = blk ? 0 : 32;   // local col -> global k-tile offset
    f32x4 acc[4] = {};
    short8 r0, r1, r2;
    // IDX<128: A-frag fi=IDX>>6, m=IDX&15, kq=(IDX>>4)&3 -> row-major P gather (16B/lane)
#define SADDR(IDX, KT) ((IDX) < 128 ? \
    (Prow + (size_t)(mt * 32 + ((IDX) >> 6) * 16 + ((IDX) & 15)) * 1024 + (KT) * 32 + (((IDX) >> 4) & 3) * 8) : \
    (WhB + ((Bb2 + (((IDX) - 128) >> 6)) * 64 + koff + (KT)) * 512 + (((IDX) - 128) & 63) * 8))
#define LOADST(KT) { \
    r0 = *(const short8*)SADDR(t, KT); \
    r1 = *(const short8*)SADDR(t + 256, KT); \
    if(t < 128) r2 = *(const short8*)SADDR(t + 512, KT); }
#define WRITEST(BUF) { \
    *(short8*)&lds[BUF][t * 8] = r0; \
    *(short8*)&lds[BUF][(t + 256) * 8] = r1; \
    if(t < 128) *(short8*)&lds[BUF][(t + 512) * 8] = r2; }
    LOADST(0)
    WRITEST(0)
    __syncthreads();
    for(int kt = 0; kt < 32; kt++){
        int cur = kt & 1;
        if(kt < 31){ LOADST(kt + 1) }
        short8 af = *(const short8*)&lds[cur][(wm * 64 + lane) * 8];
        short8 bf[4];
        #pragma unroll
        for(int ni = 0; ni < 4; ni++)
            bf[ni] = *(const short8*)&lds[cur][((2 + wn * 4 + ni) * 64 + lane) * 8];
        #pragma unroll
        for(int ni = 0; ni < 4; ni++)
            acc[ni] = __builtin_amdgcn_mfma_f32_16x16x32_bf16(af, bf[ni], acc[ni], 0, 0, 0);
        __syncthreads();
        if(kt < 31){
            WRITEST(cur ^ 1)
            __syncthreads();
        }
    }
    int rq = lane >> 4, rc = lane & 15;
    int rowg0 = (blk ? HALF : 0) + mt * 32 + wm * 16;
    #pragma unroll
    for(int ni = 0; ni < 4; ni++){
        int f = (wn * 4 + ni) * 16 + rc;
        #pragma unroll
        for(int rg = 0; rg < 4; rg++){
            float v = acc[ni][rg];
            v = v > 0.f ? v : expm1f(v);
            out[((size_t)b * NN + rowg0 + rq * 4 + rg) * (HH * FF) + h * FF + f] = v;
        }
    }
#undef SADDR
#undef LOADST
#undef WRITEST
}

extern "C" void kernel_launch(void* const* d_in, const int* in_sizes, int n_in,
                              void* d_out, int out_size, void* d_ws, size_t ws_size,
                              hipStream_t stream){
    const float* x   = (const float*)d_in[0];
    const float* wv  = (const float*)d_in[1];
    const float* W   = (const float*)d_in[2];
    const float* a   = (const float*)d_in[3];
    const int*   adj = (const int*)d_in[4];
    float* out = (float*)d_out;

    char* ws = (char*)d_ws;
    short*          P     = (short*)ws;                          // 33,554,432 B
    float*          Wh    = (float*)(ws + 33554432);             //  8,388,608 B
    short*          WhB   = (short*)(ws + 41943040);             //  4,194,304 B
    __hip_bfloat16* wvT   = (__hip_bfloat16*)(ws + 46137344);    //  4,194,304 B
    __hip_bfloat16* wvB   = (__hip_bfloat16*)(ws + 50331648);    //  4,194,304 B
    float*          sT    = (float*)(ws + 54525952);             //     65,536 B
    float*          dT    = (float*)(ws + 54591488);             //     65,536 B
    float*          denom = (float*)(ws + 54657024);             //     65,536 B

    k_transpose<<<dim3(32, 32, BB), 256, 0, stream>>>(wv, wvT, wvB);
    k_wh<<<dim3(64, HH, BB), 256, 0, stream>>>(x, W, Wh);
    k_sd<<<dim3(4096), 256, 0, stream>>>(Wh, a, sT, dT, denom);
    k_att<<<dim3(8, 32, 4), 256, 0, stream>>>(adj, wvB, wvT, sT, dT, P, denom);
    k_scale<<<dim3(64, HH, BB), 256, 0, stream>>>(Wh, denom, WhB);
    k_pv<<<dim3(32, HH, 4), 256, 0, stream>>>(P, WhB, out);
}

// Round 8
// 56.963 us; speedup vs baseline: 1.5734x; 1.2343x over previous
//
#include <hip/hip_runtime.h>
#include <hip/hip_bf16.h>
#include <math.h>

#define BB 2
#define NN 2048
#define FF 128
#define HH 4
#define HALF 1024

typedef __attribute__((ext_vector_type(8))) short short8;
typedef __attribute__((ext_vector_type(4))) short short4v;
typedef __attribute__((ext_vector_type(4))) float f32x4;

__device__ __forceinline__ short f2bf(float f){
    __hip_bfloat16 h = __float2bfloat16(f);
    return *reinterpret_cast<short*>(&h);
}
__device__ __forceinline__ float bf2f(short v){
    __hip_bfloat16 h = *reinterpret_cast<__hip_bfloat16*>(&v);
    return __bfloat162float(h);
}

// K0: wv fp32 -> wvB (bf16 row-major) + wvT (bf16 transpose)
__global__ void k_transpose(const float* __restrict__ wv, __hip_bfloat16* __restrict__ wvT,
                            __hip_bfloat16* __restrict__ wvB){
    __shared__ float tile[32][33];
    int b = blockIdx.z;
    int i0 = blockIdx.x * 32, j0 = blockIdx.y * 32;
    int tx = threadIdx.x & 31, ty = threadIdx.x >> 5;
    const float* src = wv + (size_t)b * HALF * HALF;
    __hip_bfloat16* dstT = wvT + (size_t)b * HALF * HALF;
    __hip_bfloat16* dstB = wvB + (size_t)b * HALF * HALF;
    #pragma unroll
    for(int l = 0; l < 4; l++){
        int row = ty + l * 8;
        float v = src[(size_t)(j0 + row) * HALF + (i0 + tx)];
        tile[row][tx] = v;
        dstB[(size_t)(j0 + row) * HALF + (i0 + tx)] = __float2bfloat16(v);
    }
    __syncthreads();
    #pragma unroll
    for(int l = 0; l < 4; l++){
        int row = ty + l * 8;
        dstT[(size_t)(i0 + row) * HALF + (j0 + tx)] = __float2bfloat16(tile[tx][row]);
    }
}

// K1: Wh = x @ W[h] via MFMA (bf16 in, fp32 out).
// grid (32: 64 rows, 4 h, 2 b), block 256 = 4 waves (wm=w>>1, wn=w&1).
// LDS: xs [64][136] shorts (b128 A-frag reads ~conflict-free),
//      ws [128][130] shorts (scalar B-frag reads hit all 32 banks).
__global__ __launch_bounds__(256) void k_whmm(const float* __restrict__ x,
        const float* __restrict__ W, float* __restrict__ Wh){
    __shared__ short xs[64 * 136];
    __shared__ short ws[128 * 130];
    int t = threadIdx.x;
    int w = t >> 6, lane = t & 63;
    int wm = w >> 1, wn = w & 1;
    int n0 = blockIdx.x * 64;
    int h = blockIdx.y, b = blockIdx.z;
    // stage x tile (64x128 fp32 -> bf16)
    const float* xb = x + ((size_t)b * NN + n0) * FF;
    #pragma unroll
    for(int l = 0; l < 8; l++){
        int flat4 = t + l * 256;            // 0..2047 float4s
        int row = flat4 >> 5, col4 = flat4 & 31;
        float4 v = *(const float4*)(xb + (size_t)row * FF + col4 * 4);
        short* dst = &xs[row * 136 + col4 * 4];
        dst[0] = f2bf(v.x); dst[1] = f2bf(v.y); dst[2] = f2bf(v.z); dst[3] = f2bf(v.w);
    }
    // stage W[h] (128x128 fp32 -> bf16)
    const float* Wb = W + (size_t)h * FF * FF;
    #pragma unroll
    for(int l = 0; l < 16; l++){
        int flat4 = t + l * 256;            // 0..4095
        int row = flat4 >> 5, col4 = flat4 & 31;
        float4 v = *(const float4*)(Wb + (size_t)row * FF + col4 * 4);
        short* dst = &ws[row * 130 + col4 * 4];
        dst[0] = f2bf(v.x); dst[1] = f2bf(v.y); dst[2] = f2bf(v.z); dst[3] = f2bf(v.w);
    }
    __syncthreads();
    int m = lane & 15, q = lane >> 4;
    f32x4 acc[2][4] = {};
    #pragma unroll
    for(int ks = 0; ks < 4; ks++){
        short8 af[2];
        #pragma unroll
        for(int mi = 0; mi < 2; mi++)
            af[mi] = *(const short8*)&xs[(wm * 32 + mi * 16 + m) * 136 + ks * 32 + q * 8];
        short8 bf[4];
        #pragma unroll
        for(int ni = 0; ni < 4; ni++){
            #pragma unroll
            for(int e = 0; e < 8; e++)
                bf[ni][e] = ws[(ks * 32 + q * 8 + e) * 130 + wn * 64 + ni * 16 + m];
        }
        #pragma unroll
        for(int mi = 0; mi < 2; mi++)
            #pragma unroll
            for(int ni = 0; ni < 4; ni++)
                acc[mi][ni] = __builtin_amdgcn_mfma_f32_16x16x32_bf16(af[mi], bf[ni], acc[mi][ni], 0, 0, 0);
    }
    // epilogue: C row = q*4+rg, col = m
    float* ob = Wh + (((size_t)b * HH + h) * NN + n0) * FF;
    #pragma unroll
    for(int mi = 0; mi < 2; mi++){
        #pragma unroll
        for(int ni = 0; ni < 4; ni++){
            int col = wn * 64 + ni * 16 + m;
            #pragma unroll
            for(int rg = 0; rg < 4; rg++){
                int row = wm * 32 + mi * 16 + q * 4 + rg;
                ob[(size_t)row * FF + col] = acc[mi][ni][rg];
            }
        }
    }
}

// K2: row dots -> TRANSPOSED sT/dT [b][n][h] (+ zero denom)
__global__ void k_sd(const float* __restrict__ Wh, const float* __restrict__ a,
                     float* __restrict__ sT, float* __restrict__ dT, float* __restrict__ denom){
    int gid = blockIdx.x * blockDim.x + threadIdx.x;
    if(gid < BB * HH * NN) denom[gid] = 0.f;
    int wid = threadIdx.x >> 6, lane = threadIdx.x & 63;
    int row = blockIdx.x * 4 + wid;            // row = (b*HH + h)*NN + n
    int b = row >> 13, h = (row >> 11) & 3, n = row & (NN - 1);
    const float* wr = Wh + (size_t)row * FF;
    float v0 = wr[lane], v1 = wr[lane + 64];
    const float* ah = a + (size_t)h * 2 * FF;
    float ps = v0 * ah[lane]      + v1 * ah[lane + 64];
    float pd = v0 * ah[FF + lane] + v1 * ah[FF + lane + 64];
    #pragma unroll
    for(int m = 32; m >= 1; m >>= 1){
        ps += __shfl_xor(ps, m);
        pd += __shfl_xor(pd, m);
    }
    if(lane == 0){
        sT[((size_t)b * NN + n) * HH + h] = ps;
        dT[((size_t)b * NN + n) * HH + h] = pd;
    }
}

// K3: ROW-MAJOR streaming attention: P[slice][i_loc][j_loc] bf16 + column denoms.
// grid: x = jt(8: 128 j), y = ic(32: 32 i), z = bb(4). block 256 (jlane 128 x ihalf 2).
__global__ __launch_bounds__(256) void k_att(const int* __restrict__ adj,
        const __hip_bfloat16* __restrict__ wvRM, const __hip_bfloat16* __restrict__ wvTp,
        const float* __restrict__ sT, const float* __restrict__ dT,
        short* __restrict__ P, float* __restrict__ denom){
    __shared__ float red[HH][128];
    int t = threadIdx.x;
    int jlane = t & 127, ihalf = t >> 7;
    int jt = blockIdx.x, ic = blockIdx.y, bb = blockIdx.z;
    int b = bb >> 1, blk = bb & 1;
    int jl = jt * 128 + jlane;
    int jg = blk ? jl : HALF + jl;
    int iloc0 = ic * 32 + ihalf * 16;
    int ig0 = (blk ? HALF : 0) + iloc0;
    const int* ap = adj + ((size_t)b * NN + ig0) * NN + jg;
    const short* wp = (const short*)(blk ? wvRM : wvTp) + ((size_t)b * HALF + iloc0) * HALF + jl;
    const float* sp = sT + ((size_t)b * NN + ig0) * HH;
    float4 dv4 = *(const float4*)(dT + ((size_t)b * NN + jg) * HH);
    float da[4] = {dv4.x, dv4.y, dv4.z, dv4.w};
    short* Pp = P + ((size_t)(bb * HH) << 20) + (size_t)iloc0 * 1024 + jl;
    float den[HH] = {};
    #pragma unroll 4
    for(int ii = 0; ii < 16; ii++){
        int av = ap[(size_t)ii * NN];
        short wq = wp[(size_t)ii * HALF];
        float4 s4 = *(const float4*)(sp + ii * HH);
        float wm = av > 0 ? bf2f(wq) : 0.f;
        float sa[4] = {s4.x, s4.y, s4.z, s4.w};
        #pragma unroll
        for(int h = 0; h < HH; h++){
            float tt = sa[h] + da[h];
            tt = tt > 0.f ? tt : 0.2f * tt;
            float pe = __expf(tt) * wm;
            den[h] += pe;
            Pp[((size_t)h << 20) + (size_t)ii * 1024] = f2bf(pe);
        }
    }
    if(ihalf){
        #pragma unroll
        for(int h = 0; h < HH; h++) red[h][jlane] = den[h];
    }
    __syncthreads();
    if(!ihalf){
        #pragma unroll
        for(int h = 0; h < HH; h++)
            atomicAdd(&denom[((size_t)b * HH + h) * NN + jg], den[h] + red[h][jlane]);
    }
}

// K4: WhB (bf16, MFMA-B-fragment layout) = Wh[j][f] * 1/clip(denom[j])
__global__ __launch_bounds__(256) void k_scale(const float* __restrict__ Wh,
        const float* __restrict__ denom, short* __restrict__ WhB){
    int t = threadIdx.x, w = t >> 6, lane = t & 63, q = lane >> 4, r = lane & 15;
    int kt = blockIdx.x, h = blockIdx.y, b = blockIdx.z;
    int sl = b * HH + h;
    int jb = kt * 32 + q * 8;
    const float* dp = denom + (size_t)sl * NN + jb;
    float4 D0 = *(const float4*)dp;
    float4 D1 = *(const float4*)(dp + 4);
    float dn[8] = {D0.x,D0.y,D0.z,D0.w,D1.x,D1.y,D1.z,D1.w};
    float inv[8];
    #pragma unroll
    for(int e = 0; e < 8; e++) inv[e] = 1.f / fmaxf(dn[e], 1e-12f);
    #pragma unroll
    for(int ntl = 0; ntl < 2; ntl++){
        int nt = w + ntl * 4;
        int f = nt * 16 + r;
        short8 pk;
        #pragma unroll
        for(int e = 0; e < 8; e++){
            float v = Wh[((size_t)sl * NN + jb + e) * FF + f] * inv[e];
            pk[e] = f2bf(v);
        }
        *(short8*)(WhB + (((size_t)sl * 8 + nt) * 64 + kt) * 512 + lane * 8) = pk;
    }
}

// K5: out = ELU(P @ WhB). BM=32, grid (32,4,4)=512 blocks, 4 waves (2m x 2n).
// A staged from row-major P via 64B row-segments into padded [32][40]-short LDS tile;
// B frags contiguous. Per buf: A 2560 + B 4096 shorts = 6656.
__global__ __launch_bounds__(256) void k_pv(const short* __restrict__ P,
        const short* __restrict__ WhB, float* __restrict__ out){
    __shared__ short lds[2][6656];
    int t = threadIdx.x;
    int w = t >> 6, lane = t & 63;
    int wm = w >> 1, wn = w & 1;
    int mt = blockIdx.x, h = blockIdx.y, bb = blockIdx.z;
    int b = bb >> 1, blk = bb & 1;
    const short* Prow = P + ((size_t)(bb * HH + h) << 20);   // [1024][1024] local
    size_t Bb2 = ((size_t)b * HH + h) * 8;
    int koff = blk ? 0 : 32;
    int rowA = t >> 3, c8 = t & 7;             // A-stage: 8 threads x 8B per row
    const short* srcA0 = Prow + (size_t)(mt * 32 + rowA) * 1024 + c8 * 4;
    f32x4 acc[4] = {};
    short4v r0; short8 r1, r2;
#define LOADST(KT) { \
    r0 = *(const short4v*)(srcA0 + (KT) * 32); \
    r1 = *(const short8*)(WhB + ((Bb2 + (t >> 6)) * 64 + koff + (KT)) * 512 + (t & 63) * 8); \
    r2 = *(const short8*)(WhB + ((Bb2 + 4 + (t >> 6)) * 64 + koff + (KT)) * 512 + (t & 63) * 8); }
#define WRITEST(BUF) { \
    *(short4v*)&lds[BUF][rowA * 40 + c8 * 4] = r0; \
    *(short8*)&lds[BUF][2560 + (t >> 6) * 512 + (t & 63) * 8] = r1; \
    *(short8*)&lds[BUF][2560 + 2048 + (t >> 6) * 512 + (t & 63) * 8] = r2; }
    LOADST(0)
    WRITEST(0)
    __syncthreads();
    int m = lane & 15, q = lane >> 4;
    for(int kt = 0; kt < 32; kt++){
        int cur = kt & 1;
        if(kt < 31){ LOADST(kt + 1) }
        short8 af = *(const short8*)&lds[cur][(wm * 16 + m) * 40 + q * 8];
        short8 bf[4];
        #pragma unroll
        for(int ni = 0; ni < 4; ni++)
            bf[ni] = *(const short8*)&lds[cur][2560 + (wn * 4 + ni) * 512 + lane * 8];
        #pragma unroll
        for(int ni = 0; ni < 4; ni++)
            acc[ni] = __builtin_amdgcn_mfma_f32_16x16x32_bf16(af, bf[ni], acc[ni], 0, 0, 0);
        __syncthreads();
        if(kt < 31){
            WRITEST(cur ^ 1)
            __syncthreads();
        }
    }
    int rq = lane >> 4, rc = lane & 15;
    int rowg0 = (blk ? HALF : 0) + mt * 32 + wm * 16;
    #pragma unroll
    for(int ni = 0; ni < 4; ni++){
        int f = (wn * 4 + ni) * 16 + rc;
        #pragma unroll
        for(int rg = 0; rg < 4; rg++){
            float v = acc[ni][rg];
            v = v > 0.f ? v : expm1f(v);
            out[((size_t)b * NN + rowg0 + rq * 4 + rg) * (HH * FF) + h * FF + f] = v;
        }
    }
#undef LOADST
#undef WRITEST
}

extern "C" void kernel_launch(void* const* d_in, const int* in_sizes, int n_in,
                              void* d_out, int out_size, void* d_ws, size_t ws_size,
                              hipStream_t stream){
    const float* x   = (const float*)d_in[0];
    const float* wv  = (const float*)d_in[1];
    const float* W   = (const float*)d_in[2];
    const float* a   = (const float*)d_in[3];
    const int*   adj = (const int*)d_in[4];
    float* out = (float*)d_out;

    char* ws = (char*)d_ws;
    short*          P     = (short*)ws;                          // 33,554,432 B
    float*          Wh    = (float*)(ws + 33554432);             //  8,388,608 B
    short*          WhB   = (short*)(ws + 41943040);             //  4,194,304 B
    __hip_bfloat16* wvT   = (__hip_bfloat16*)(ws + 46137344);    //  4,194,304 B
    __hip_bfloat16* wvB   = (__hip_bfloat16*)(ws + 50331648);    //  4,194,304 B
    float*          sT    = (float*)(ws + 54525952);             //     65,536 B
    float*          dT    = (float*)(ws + 54591488);             //     65,536 B
    float*          denom = (float*)(ws + 54657024);             //     65,536 B

    k_transpose<<<dim3(32, 32, BB), 256, 0, stream>>>(wv, wvT, wvB);
    k_whmm<<<dim3(32, HH, BB), 256, 0, stream>>>(x, W, Wh);
    k_sd<<<dim3(4096), 256, 0, stream>>>(Wh, a, sT, dT, denom);
    k_att<<<dim3(8, 32, 4), 256, 0, stream>>>(adj, wvB, wvT, sT, dT, P, denom);
    k_scale<<<dim3(64, HH, BB), 256, 0, stream>>>(Wh, denom, WhB);
    k_pv<<<dim3(32, HH, 4), 256, 0, stream>>>(P, WhB, out);
}

// Round 9
// 48.338 us; speedup vs baseline: 1.8541x; 1.1784x over previous
//
#include <hip/hip_runtime.h>
#include <hip/hip_bf16.h>
#include <math.h>

#define BB 2
#define NN 2048
#define FF 128
#define HH 4
#define HALF 1024

typedef __attribute__((ext_vector_type(8))) short short8;
typedef __attribute__((ext_vector_type(4))) short short4v;
typedef __attribute__((ext_vector_type(4))) float f32x4;

__device__ __forceinline__ short f2bf(float f){
    __hip_bfloat16 h = __float2bfloat16(f);
    return *reinterpret_cast<short*>(&h);
}
__device__ __forceinline__ float bf2f(short v){
    __hip_bfloat16 h = *reinterpret_cast<__hip_bfloat16*>(&v);
    return __bfloat162float(h);
}

// K1: Wh = x @ W[h] via MFMA (bf16 in, fp32 out) + FUSED s/d row-dots + denom zero.
// grid (32: 64 rows, 4 h, 2 b), block 256 = 4 waves (wm=w>>1, wn=w&1).
__global__ __launch_bounds__(256) void k_whmm(const float* __restrict__ x,
        const float* __restrict__ W, const float* __restrict__ a,
        float* __restrict__ Wh, float* __restrict__ sT, float* __restrict__ dT,
        float* __restrict__ denom){
    __shared__ short xs[64 * 136];
    __shared__ short ws_[128 * 130];
    __shared__ float red_s[2][64], red_d[2][64];
    int t = threadIdx.x;
    int w = t >> 6, lane = t & 63;
    int wm = w >> 1, wn = w & 1;
    int n0 = blockIdx.x * 64;
    int h = blockIdx.y, b = blockIdx.z;
    // zero denom chunk (16384 entries / 256 blocks = 64 each)
    int flat = blockIdx.x + 32 * (blockIdx.y + HH * blockIdx.z);
    if(t < 64) denom[flat * 64 + t] = 0.f;
    // stage x tile (64x128 fp32 -> bf16)
    const float* xb = x + ((size_t)b * NN + n0) * FF;
    #pragma unroll
    for(int l = 0; l < 8; l++){
        int flat4 = t + l * 256;
        int row = flat4 >> 5, col4 = flat4 & 31;
        float4 v = *(const float4*)(xb + (size_t)row * FF + col4 * 4);
        short* dst = &xs[row * 136 + col4 * 4];
        dst[0] = f2bf(v.x); dst[1] = f2bf(v.y); dst[2] = f2bf(v.z); dst[3] = f2bf(v.w);
    }
    // stage W[h] (128x128 fp32 -> bf16)
    const float* Wb = W + (size_t)h * FF * FF;
    #pragma unroll
    for(int l = 0; l < 16; l++){
        int flat4 = t + l * 256;
        int row = flat4 >> 5, col4 = flat4 & 31;
        float4 v = *(const float4*)(Wb + (size_t)row * FF + col4 * 4);
        short* dst = &ws_[row * 130 + col4 * 4];
        dst[0] = f2bf(v.x); dst[1] = f2bf(v.y); dst[2] = f2bf(v.z); dst[3] = f2bf(v.w);
    }
    __syncthreads();
    int m = lane & 15, q = lane >> 4;
    f32x4 acc[2][4] = {};
    #pragma unroll
    for(int ks = 0; ks < 4; ks++){
        short8 af[2];
        #pragma unroll
        for(int mi = 0; mi < 2; mi++)
            af[mi] = *(const short8*)&xs[(wm * 32 + mi * 16 + m) * 136 + ks * 32 + q * 8];
        short8 bf[4];
        #pragma unroll
        for(int ni = 0; ni < 4; ni++){
            #pragma unroll
            for(int e = 0; e < 8; e++)
                bf[ni][e] = ws_[(ks * 32 + q * 8 + e) * 130 + wn * 64 + ni * 16 + m];
        }
        #pragma unroll
        for(int mi = 0; mi < 2; mi++)
            #pragma unroll
            for(int ni = 0; ni < 4; ni++)
                acc[mi][ni] = __builtin_amdgcn_mfma_f32_16x16x32_bf16(af[mi], bf[ni], acc[mi][ni], 0, 0, 0);
    }
    // write Wh; C row = q*4+rg, col = m
    float* ob = Wh + (((size_t)b * HH + h) * NN + n0) * FF;
    #pragma unroll
    for(int mi = 0; mi < 2; mi++){
        #pragma unroll
        for(int ni = 0; ni < 4; ni++){
            int col = wn * 64 + ni * 16 + m;
            #pragma unroll
            for(int rg = 0; rg < 4; rg++){
                int row = wm * 32 + mi * 16 + q * 4 + rg;
                ob[(size_t)row * FF + col] = acc[mi][ni][rg];
            }
        }
    }
    // fused s/d: per-thread partial over its 4 cols, shfl-reduce over m, LDS over wn
    float asrc[4], adst[4];
    const float* ah = a + (size_t)h * 2 * FF;
    #pragma unroll
    for(int ni = 0; ni < 4; ni++){
        int col = wn * 64 + ni * 16 + m;
        asrc[ni] = ah[col];
        adst[ni] = ah[FF + col];
    }
    #pragma unroll
    for(int mi = 0; mi < 2; mi++){
        #pragma unroll
        for(int rg = 0; rg < 4; rg++){
            float ps = 0.f, pd = 0.f;
            #pragma unroll
            for(int ni = 0; ni < 4; ni++){
                ps += acc[mi][ni][rg] * asrc[ni];
                pd += acc[mi][ni][rg] * adst[ni];
            }
            #pragma unroll
            for(int msk = 8; msk >= 1; msk >>= 1){
                ps += __shfl_xor(ps, msk);
                pd += __shfl_xor(pd, msk);
            }
            if(m == 0){
                int row = wm * 32 + mi * 16 + q * 4 + rg;
                red_s[wn][row] = ps;
                red_d[wn][row] = pd;
            }
        }
    }
    __syncthreads();
    if(t < 64){
        int n = n0 + t;
        sT[((size_t)b * NN + n) * HH + h] = red_s[0][t] + red_s[1][t];
        dT[((size_t)b * NN + n) * HH + h] = red_d[0][t] + red_d[1][t];
    }
}

// K3: ROW-MAJOR streaming attention from RAW fp32 wv: P[slice][i][j] bf16 + col denoms.
// blk=1: wv row-major (lane-coalesced); blk=0: wv[jl][i] (per-thread contiguous, L1-hot).
// grid: x = jt(8: 128 j), y = ic(32: 32 i), z = bb(4). block 256 (jlane 128 x ihalf 2).
__global__ __launch_bounds__(256) void k_att(const int* __restrict__ adj,
        const float* __restrict__ wv,
        const float* __restrict__ sT, const float* __restrict__ dT,
        short* __restrict__ P, float* __restrict__ denom){
    __shared__ float red[HH][128];
    int t = threadIdx.x;
    int jlane = t & 127, ihalf = t >> 7;
    int jt = blockIdx.x, ic = blockIdx.y, bb = blockIdx.z;
    int b = bb >> 1, blk = bb & 1;
    int jl = jt * 128 + jlane;
    int jg = blk ? jl : HALF + jl;
    int iloc0 = ic * 32 + ihalf * 16;
    int ig0 = (blk ? HALF : 0) + iloc0;
    const int* ap = adj + ((size_t)b * NN + ig0) * NN + jg;
    const float* sp = sT + ((size_t)b * NN + ig0) * HH;
    float4 dv4 = *(const float4*)(dT + ((size_t)b * NN + jg) * HH);
    float da[4] = {dv4.x, dv4.y, dv4.z, dv4.w};
    short* Pp = P + ((size_t)(bb * HH) << 20) + (size_t)iloc0 * 1024 + jl;
    float den[HH] = {};
#define ATTLOOP(WPTR, WSTRIDE) \
    _Pragma("unroll 4") \
    for(int ii = 0; ii < 16; ii++){ \
        int av = ap[(size_t)ii * NN]; \
        float wq = (WPTR)[(size_t)ii * (WSTRIDE)]; \
        float4 s4 = *(const float4*)(sp + ii * HH); \
        float wmv = av > 0 ? wq : 0.f; \
        float sa[4] = {s4.x, s4.y, s4.z, s4.w}; \
        _Pragma("unroll") \
        for(int h = 0; h < HH; h++){ \
            float tt = sa[h] + da[h]; \
            tt = tt > 0.f ? tt : 0.2f * tt; \
            float pe = __expf(tt) * wmv; \
            den[h] += pe; \
            Pp[((size_t)h << 20) + (size_t)ii * 1024] = f2bf(pe); \
        } \
    }
    if(blk){
        const float* wp = wv + ((size_t)b * HALF + iloc0) * HALF + jl;
        ATTLOOP(wp, HALF)
    } else {
        const float* wp = wv + ((size_t)b * HALF + jl) * HALF + iloc0;
        ATTLOOP(wp, 1)
    }
#undef ATTLOOP
    if(ihalf){
        #pragma unroll
        for(int h = 0; h < HH; h++) red[h][jlane] = den[h];
    }
    __syncthreads();
    if(!ihalf){
        #pragma unroll
        for(int h = 0; h < HH; h++)
            atomicAdd(&denom[((size_t)b * HH + h) * NN + jg], den[h] + red[h][jlane]);
    }
}

// K4: WhB (bf16, MFMA-B-fragment layout) = Wh[j][f] * 1/clip(denom[j])
__global__ __launch_bounds__(256) void k_scale(const float* __restrict__ Wh,
        const float* __restrict__ denom, short* __restrict__ WhB){
    int t = threadIdx.x, w = t >> 6, lane = t & 63, q = lane >> 4, r = lane & 15;
    int kt = blockIdx.x, h = blockIdx.y, b = blockIdx.z;
    int sl = b * HH + h;
    int jb = kt * 32 + q * 8;
    const float* dp = denom + (size_t)sl * NN + jb;
    float4 D0 = *(const float4*)dp;
    float4 D1 = *(const float4*)(dp + 4);
    float dn[8] = {D0.x,D0.y,D0.z,D0.w,D1.x,D1.y,D1.z,D1.w};
    float inv[8];
    #pragma unroll
    for(int e = 0; e < 8; e++) inv[e] = 1.f / fmaxf(dn[e], 1e-12f);
    #pragma unroll
    for(int ntl = 0; ntl < 2; ntl++){
        int nt = w + ntl * 4;
        int f = nt * 16 + r;
        short8 pk;
        #pragma unroll
        for(int e = 0; e < 8; e++){
            float v = Wh[((size_t)sl * NN + jb + e) * FF + f] * inv[e];
            pk[e] = f2bf(v);
        }
        *(short8*)(WhB + (((size_t)sl * 8 + nt) * 64 + kt) * 512 + lane * 8) = pk;
    }
}

// K5: out = ELU(P @ WhB). BM=32, grid (32,4,4)=512 blocks, 4 waves (2m x 2n).
// A staged from row-major P via 64B row-segments into padded [32][40]-short LDS tile.
__global__ __launch_bounds__(256) void k_pv(const short* __restrict__ P,
        const short* __restrict__ WhB, float* __restrict__ out){
    __shared__ short lds[2][6656];
    int t = threadIdx.x;
    int w = t >> 6, lane = t & 63;
    int wm = w >> 1, wn = w & 1;
    int mt = blockIdx.x, h = blockIdx.y, bb = blockIdx.z;
    int b = bb >> 1, blk = bb & 1;
    const short* Prow = P + ((size_t)(bb * HH + h) << 20);
    size_t Bb2 = ((size_t)b * HH + h) * 8;
    int koff = blk ? 0 : 32;
    int rowA = t >> 3, c8 = t & 7;
    const short* srcA0 = Prow + (size_t)(mt * 32 + rowA) * 1024 + c8 * 4;
    f32x4 acc[4] = {};
    short4v r0; short8 r1, r2;
#define LOADST(KT) { \
    r0 = *(const short4v*)(srcA0 + (KT) * 32); \
    r1 = *(const short8*)(WhB + ((Bb2 + (t >> 6)) * 64 + koff + (KT)) * 512 + (t & 63) * 8); \
    r2 = *(const short8*)(WhB + ((Bb2 + 4 + (t >> 6)) * 64 + koff + (KT)) * 512 + (t & 63) * 8); }
#define WRITEST(BUF) { \
    *(short4v*)&lds[BUF][rowA * 40 + c8 * 4] = r0; \
    *(short8*)&lds[BUF][2560 + (t >> 6) * 512 + (t & 63) * 8] = r1; \
    *(short8*)&lds[BUF][2560 + 2048 + (t >> 6) * 512 + (t & 63) * 8] = r2; }
    LOADST(0)
    WRITEST(0)
    __syncthreads();
    int m = lane & 15, q = lane >> 4;
    for(int kt = 0; kt < 32; kt++){
        int cur = kt & 1;
        if(kt < 31){ LOADST(kt + 1) }
        short8 af = *(const short8*)&lds[cur][(wm * 16 + m) * 40 + q * 8];
        short8 bf[4];
        #pragma unroll
        for(int ni = 0; ni < 4; ni++)
            bf[ni] = *(const short8*)&lds[cur][2560 + (wn * 4 + ni) * 512 + lane * 8];
        #pragma unroll
        for(int ni = 0; ni < 4; ni++)
            acc[ni] = __builtin_amdgcn_mfma_f32_16x16x32_bf16(af, bf[ni], acc[ni], 0, 0, 0);
        __syncthreads();
        if(kt < 31){
            WRITEST(cur ^ 1)
            __syncthreads();
        }
    }
    int rq = lane >> 4, rc = lane & 15;
    int rowg0 = (blk ? HALF : 0) + mt * 32 + wm * 16;
    #pragma unroll
    for(int ni = 0; ni < 4; ni++){
        int f = (wn * 4 + ni) * 16 + rc;
        #pragma unroll
        for(int rg = 0; rg < 4; rg++){
            float v = acc[ni][rg];
            v = v > 0.f ? v : expm1f(v);
            out[((size_t)b * NN + rowg0 + rq * 4 + rg) * (HH * FF) + h * FF + f] = v;
        }
    }
#undef LOADST
#undef WRITEST
}

extern "C" void kernel_launch(void* const* d_in, const int* in_sizes, int n_in,
                              void* d_out, int out_size, void* d_ws, size_t ws_size,
                              hipStream_t stream){
    const float* x   = (const float*)d_in[0];
    const float* wv  = (const float*)d_in[1];
    const float* W   = (const float*)d_in[2];
    const float* a   = (const float*)d_in[3];
    const int*   adj = (const int*)d_in[4];
    float* out = (float*)d_out;

    char* ws = (char*)d_ws;
    short* P     = (short*)ws;                   // 33,554,432 B
    float* Wh    = (float*)(ws + 33554432);      //  8,388,608 B
    short* WhB   = (short*)(ws + 41943040);      //  4,194,304 B
    float* sT    = (float*)(ws + 46137344);      //     65,536 B
    float* dT    = (float*)(ws + 46202880);      //     65,536 B
    float* denom = (float*)(ws + 46268416);      //     65,536 B

    k_whmm<<<dim3(32, HH, BB), 256, 0, stream>>>(x, W, a, Wh, sT, dT, denom);
    k_att<<<dim3(8, 32, 4), 256, 0, stream>>>(adj, wv, sT, dT, P, denom);
    k_scale<<<dim3(64, HH, BB), 256, 0, stream>>>(Wh, denom, WhB);
    k_pv<<<dim3(32, HH, 4), 256, 0, stream>>>(P, WhB, out);
}